// Round 9
// baseline (1966.673 us; speedup 1.0000x reference)
//
#include <hip/hip_runtime.h>
#include <hip/hip_bf16.h>
#include <math.h>

#define H_SIZE 768
#define N_HEADS 12
#define HEAD 64
#define INTER 3072
#define N_LAYERS 6
#define BATCH 4
#define SEQ 2048
#define BS (BATCH*SEQ)
#define EPSV 1e-6f

typedef __attribute__((ext_vector_type(8))) short bf16x8;
typedef __attribute__((ext_vector_type(4))) float f32x4;
typedef unsigned short u16;

__device__ inline float bf2f(u16 v) {
    union { float f; unsigned u; } x; x.u = ((unsigned)v) << 16; return x.f;
}
__device__ inline u16 f2bf(float f) {
    union { float f; unsigned u; } x; x.f = f;
    unsigned u = x.u;
    return (u16)((u + 0x7FFFu + ((u >> 16) & 1u)) >> 16);
}

// async global->LDS, 16B per lane. LDS dest = wave-uniform base + lane*16.
__device__ __forceinline__ void stage16(const u16* g, u16* ldsbase) {
    __builtin_amdgcn_global_load_lds((const __attribute__((address_space(1))) void*)g,
                                     (__attribute__((address_space(3))) void*)ldsbase,
                                     16, 0, 0);
}

// ---------------- dtype probe ----------------
__global__ void probe_kernel(const u16* __restrict__ embed, const int* __restrict__ tokens,
                             int* __restrict__ flags) {
    if (threadIdx.x == 0 && blockIdx.x == 0) {
        int good = 0, evenzero = 0;
        for (int i = 0; i < 128; i++) {
            u16 h = embed[i];
            int e = (h >> 7) & 0xFF;
            if (h == 0 || (e >= 87 && e <= 133)) good++;
            if ((i & 1) == 0 && h == 0) evenzero++;
        }
        flags[0] = (evenzero >= 48) ? 1 : ((good >= 110) ? 0 : 1);
        int z = 0;
        for (int i = 0; i < 64; i++) if (tokens[2 * i + 1] == 0) z++;
        flags[1] = (z >= 60) ? 1 : 0;
    }
}

// ---------------- sincos table ----------------
__global__ __launch_bounds__(256) void sincos_kernel(const void* __restrict__ ages,
                                                     float* __restrict__ SIN,
                                                     float* __restrict__ COS,
                                                     const int* __restrict__ flags) {
    int idx = blockIdx.x * 256 + threadIdx.x;
    if (idx >= BS * 32) return;
    bool f32in = flags[0] != 0;
    int row = idx >> 5, f = idx & 31;
    float age = f32in ? ((const float*)ages)[row] : bf2f(((const u16*)ages)[row]);
    float inv = expf(-(2.0f * (float)f / 31.0f) * 9.210340371976184f);
    float t = age * inv;
    SIN[idx] = sinf(t);
    COS[idx] = cosf(t);
}

// ---------------- weight transpose+convert (batched over layers via z) ----------------
__global__ __launch_bounds__(256) void wtrans_kernel(const void* __restrict__ Wsrc,
                                                     u16* __restrict__ Wt,
                                                     int K, int N, size_t ltstride,
                                                     const int* __restrict__ flags) {
    __shared__ u16 tile[64][72];
    bool f32in = flags[0] != 0;
    int l = blockIdx.z;
    const float* W32 = (const float*)Wsrc + (size_t)l * K * N;
    const u16*   W16 = (const u16*)Wsrc + (size_t)l * K * N;
    u16* out = Wt + (size_t)l * ltstride;
    int k0 = blockIdx.y * 64, n0 = blockIdx.x * 64;
    int t = threadIdx.x;
    int kk = t >> 3, nn = (t & 7) * 8;
#pragma unroll
    for (int it = 0; it < 2; it++) {
        int kr = kk + it * 32;
        u16 tmp[8];
        if (f32in) {
            const float* src = W32 + (size_t)(k0 + kr) * N + n0 + nn;
            float4 f0 = *(const float4*)src, f1 = *(const float4*)(src + 4);
            tmp[0] = f2bf(f0.x); tmp[1] = f2bf(f0.y); tmp[2] = f2bf(f0.z); tmp[3] = f2bf(f0.w);
            tmp[4] = f2bf(f1.x); tmp[5] = f2bf(f1.y); tmp[6] = f2bf(f1.z); tmp[7] = f2bf(f1.w);
        } else {
            uint4 v = *(const uint4*)(W16 + (size_t)(k0 + kr) * N + n0 + nn);
            const u16* pv = (const u16*)&v;
#pragma unroll
            for (int i = 0; i < 8; i++) tmp[i] = pv[i];
        }
        *(uint4*)(&tile[kr][nn]) = *(const uint4*)tmp;
    }
    __syncthreads();
    int n = t >> 3, kq = (t & 7) * 8;
#pragma unroll
    for (int it = 0; it < 2; it++) {
        int nr = n + it * 32;
        u16 tmp[8];
#pragma unroll
        for (int i = 0; i < 8; i++) tmp[i] = tile[kq + i][nr];
        *(uint4*)(out + (size_t)(n0 + nr) * K + k0 + kq) = *(const uint4*)tmp;
    }
}

// ---------------- bias convert to bf16 ----------------
__global__ __launch_bounds__(256) void bias_conv_kernel(const void* __restrict__ ab,
                                                        const void* __restrict__ ib,
                                                        const void* __restrict__ ob,
                                                        u16* __restrict__ dst,
                                                        const int* __restrict__ flags) {
    int i = blockIdx.x * 256 + threadIdx.x;
    bool f32in = flags[0] != 0;
    const int A = 6 * 2304, B = 6 * 3072, C = 6 * 768;
    if (i < A) dst[i] = f32in ? f2bf(((const float*)ab)[i]) : ((const u16*)ab)[i];
    else if (i < A + B) { int j = i - A; dst[i] = f32in ? f2bf(((const float*)ib)[j]) : ((const u16*)ib)[j]; }
    else if (i < A + B + C) { int j = i - A - B; dst[i] = f32in ? f2bf(((const float*)ob)[j]) : ((const u16*)ob)[j]; }
}

// ---------------- embed gather + rmsnorm (f32 out) ----------------
__global__ __launch_bounds__(256) void embed_norm_kernel(const int* __restrict__ tokens,
                                                         const void* __restrict__ embed,
                                                         const void* __restrict__ wbase,
                                                         float* __restrict__ X,
                                                         const int* __restrict__ flags) {
    int row = blockIdx.x * 4 + (threadIdx.x >> 6);
    int lane = threadIdx.x & 63;
    bool f32in = flags[0] != 0;
    bool i64 = flags[1] != 0;
    int tok = i64 ? tokens[2 * row] : tokens[row];
    tok &= 65535;
    const u16* er16 = (const u16*)embed + (size_t)tok * H_SIZE;
    const float* er32 = (const float*)embed + (size_t)tok * H_SIZE;
    const u16* w16 = (const u16*)wbase;
    const float* w32 = (const float*)wbase;
    float v[12]; float ss = 0.f;
#pragma unroll
    for (int k = 0; k < 12; k++) {
        int i = lane + k * 64;
        float t = f32in ? er32[i] : bf2f(er16[i]);
        v[k] = t; ss += t * t;
    }
#pragma unroll
    for (int off = 1; off < 64; off <<= 1) ss += __shfl_xor(ss, off, 64);
    float scale = rsqrtf(ss * (1.0f / 768.0f) + EPSV);
#pragma unroll
    for (int k = 0; k < 12; k++) {
        int i = lane + k * 64;
        float wv = f32in ? w32[i] : bf2f(w16[i]);
        X[(size_t)row * H_SIZE + i] = v[k] * scale * wv;
    }
}

// ---------------- rmsnorm f32 -> bf16 / flag-typed final ----------------
__global__ __launch_bounds__(256) void rmsnorm_kernel(const float* __restrict__ X,
                                                      const void* __restrict__ wbase, size_t woff,
                                                      void* __restrict__ Y, int outMode,
                                                      const int* __restrict__ flags) {
    int row = blockIdx.x * 4 + (threadIdx.x >> 6);
    int lane = threadIdx.x & 63;
    bool f32in = flags[0] != 0;
    const u16* w16 = (const u16*)wbase + woff;
    const float* w32 = (const float*)wbase + woff;
    const float* xr = X + (size_t)row * H_SIZE;
    float v[12]; float ss = 0.f;
#pragma unroll
    for (int k = 0; k < 12; k++) { v[k] = xr[lane + k * 64]; ss += v[k] * v[k]; }
#pragma unroll
    for (int off = 1; off < 64; off <<= 1) ss += __shfl_xor(ss, off, 64);
    float scale = rsqrtf(ss * (1.0f / 768.0f) + EPSV);
    bool of32 = outMode && f32in;
#pragma unroll
    for (int k = 0; k < 12; k++) {
        int i = lane + k * 64;
        float wv = f32in ? w32[i] : bf2f(w16[i]);
        float val = v[k] * scale * wv;
        if (of32) ((float*)Y)[(size_t)row * H_SIZE + i] = val;
        else      ((u16*)Y)[(size_t)row * H_SIZE + i] = f2bf(val);
    }
}

// ---------------- bf16 MFMA GEMM: BMxBN tile, 3-buffer counted-vmcnt pipeline ----------------
// BM=256: 8 waves (512 thr), wave tile 64x128, acc[4][8].  BM=128: 4 waves, wave tile 64x32.
// Per iter: vmcnt(loadsPerStage) -> s_barrier -> STAGE(cur+2) -> setprio(1) MFMA setprio(0).
// 2D-chunked XCD order (L2 reuse), source/read XOR-swizzled LDS (conflict-free, r6-verified).
template <int EPI, int BM, int BN, int MGRP>
__global__ __launch_bounds__(BM == 256 ? 512 : 256)
void gemm_kernel(const u16* __restrict__ A,
                 const u16* __restrict__ Wt,
                 const u16* __restrict__ abias,
                 const u16* __restrict__ bbias,
                 float* __restrict__ Cf,
                 u16* __restrict__ qkvb,
                 u16* __restrict__ combb,
                 int K,
                 const float* __restrict__ SIN,
                 const float* __restrict__ COS) {
    constexpr int WAVES = (BM == 256) ? 8 : 4;
    constexpr int NJ = BN / 64;            // wave n-frags: BN=256 -> 4? no: BN/(2*16)... set below
    constexpr int WaveN = BN / 2;          // wave n-width (WN_WAVES=2 in both configs)
    constexpr int NF = WaveN / 16;         // n fragments per wave (8 or 2)
    constexpr int RB = BN / WAVES;         // B rows staged per wave (32 or 16)
    constexpr int LPS = 2 + RB / 16;       // gload_lds per wave per STAGE (4 or 3)
    (void)NJ;
    __shared__ u16 Al[3][BM][32];
    __shared__ u16 Bl[3][BN][32];
    const int tid = threadIdx.x;
    const int lane = tid & 63, wave = tid >> 6;
    const int wm = wave >> 1, wn = wave & 1;
    const int lm = lane & 15, g = lane >> 4;

    const int nx = gridDim.x;
    const int mpx = gridDim.y >> 3;
    int linear = blockIdx.y * nx + blockIdx.x;
    const int xcd = linear & 7;
    int wch = linear >> 3;
    const int grpsz = MGRP * nx;
    int grp = wch / grpsz;
    int rem = wch - grp * grpsz;
    int n_idx = rem / MGRP;
    int m_loc = grp * MGRP + (rem - n_idx * MGRP);
    const int m0 = (xcd * mpx + m_loc) * BM;
    const int n0 = n_idx * BN;

    f32x4 acc[4][NF];
#pragma unroll
    for (int i = 0; i < 4; i++)
#pragma unroll
        for (int j = 0; j < NF; j++) acc[i][j] = (f32x4)0.0f;

    const int swcol = ((lane & 3) ^ ((lane >> 3) & 3)) * 8;
    const u16* ga = A  + (size_t)(m0 + wave * (BM / WAVES) + (lane >> 2)) * K + swcol;
    const u16* gb = Wt + (size_t)(n0 + wave * RB + (lane >> 2)) * K + swcol;

    auto STAGE = [&](int bi, int kk) {
        stage16(ga + kk, &Al[bi][wave * (BM / WAVES)][0]);
        stage16(ga + (size_t)16 * K + kk, &Al[bi][wave * (BM / WAVES) + 16][0]);
        stage16(gb + kk, &Bl[bi][wave * RB][0]);
        if constexpr (RB == 32) stage16(gb + (size_t)16 * K + kk, &Bl[bi][wave * RB + 16][0]);
    };

    STAGE(0, 0);
    STAGE(1, 32);
    int cur = 0;
    const int cc = (g ^ ((lm >> 1) & 3)) * 8;
    for (int k0 = 0; k0 < K; k0 += 32) {
        if (k0 + 32 < K) {
            asm volatile("s_waitcnt vmcnt(%0)" :: "i"(LPS) : "memory");
        } else {
            asm volatile("s_waitcnt vmcnt(0)" ::: "memory");
        }
        __builtin_amdgcn_s_barrier();
        if (k0 + 64 < K) {
            int nx2 = cur + 2; if (nx2 >= 3) nx2 -= 3;
            STAGE(nx2, k0 + 64);   // issued after barrier; flies under this iter's MFMA
        }
        bf16x8 a[4], b[NF];
#pragma unroll
        for (int i = 0; i < 4; i++) a[i] = *(const bf16x8*)(&Al[cur][wm * 64 + i * 16 + lm][cc]);
#pragma unroll
        for (int j = 0; j < NF; j++) b[j] = *(const bf16x8*)(&Bl[cur][wn * WaveN + j * 16 + lm][cc]);
        __builtin_amdgcn_s_setprio(1);
#pragma unroll
        for (int i = 0; i < 4; i++)
#pragma unroll
            for (int j = 0; j < NF; j++)
                acc[i][j] = __builtin_amdgcn_mfma_f32_16x16x32_bf16(a[i], b[j], acc[i][j], 0, 0, 0);
        __builtin_amdgcn_s_setprio(0);
        cur += 1; if (cur >= 3) cur = 0;
    }

#pragma unroll
    for (int i = 0; i < 4; i++) {
        int mbase = m0 + wm * 64 + i * 16 + g * 4;
#pragma unroll
        for (int j = 0; j < NF; j++) {
            int n = n0 + wn * WaveN + j * 16 + lm;
            float bv;
            if (EPI == 0) bv = (n < 2304) ? bf2f(abias[n]) : bf2f(bbias[n - 2304]);
            else          bv = bf2f(abias[n]);
#pragma unroll
            for (int r = 0; r < 4; r++) {
                float v = acc[i][j][r] + bv;
                int mm = mbase + r;
                if (EPI == 0) {
                    float p = __shfl_xor(v, 1);
                    if (n < 2304) {
                        float outv = v;
                        if (n < 1536) {
                            int f = (n >> 1) & 31;
                            float c = COS[mm * 32 + f], s = SIN[mm * 32 + f];
                            outv = (n & 1) ? (v * c + p * s) : (v * c - p * s);
                        }
                        qkvb[(size_t)mm * 2304 + n] = f2bf(outv);
                    } else {
                        float u = 0.7978845608f * (v + 0.044715f * v * v * v);
                        float e = __expf(2.0f * u);
                        float th = 1.0f - 2.0f / (e + 1.0f);
                        combb[(size_t)mm * 3840 + (n - 1536)] = f2bf(0.5f * v * (1.0f + th));
                    }
                } else {
                    Cf[(size_t)mm * 768 + n] += v;
                }
            }
        }
    }
}

// ---------------- windowed flash attention ----------------
__global__ __launch_bounds__(256) void attn_kernel(const u16* __restrict__ qkv,
                                                   u16* __restrict__ Out) {
    __shared__ u16 Qs[64][72];
    __shared__ u16 Ks[64][72];
    __shared__ u16 Vt[64][72];
    __shared__ u16 Ps[4][16][72];

    const int tid = threadIdx.x;
    const int lane = tid & 63, wave = tid >> 6;
    const int lm = lane & 15, g = lane >> 4;
    const int q0 = blockIdx.x * 64;
    const int h = blockIdx.y;
    const int b = blockIdx.z;
    const size_t rowbase = (size_t)b * SEQ;

#pragma unroll
    for (int it = 0; it < 2; ++it) {
        int idx = tid + it * 256;
        int r = idx >> 3, u = (idx & 7) * 8;
        uint4 v = *(const uint4*)(qkv + (rowbase + q0 + r) * 2304 + h * HEAD + u);
        *(uint4*)(&Qs[r][u]) = v;
    }

    float m_r[4], l_r[4];
    f32x4 o[4];
#pragma unroll
    for (int r = 0; r < 4; r++) { m_r[r] = -INFINITY; l_r[r] = 0.f; }
#pragma unroll
    for (int d = 0; d < 4; d++) o[d] = (f32x4)0.0f;

    const int c_start = (q0 < 512) ? ((512 - q0) >> 6) : 0;
    for (int c = c_start; c < 9; ++c) {
        int kc = q0 - 512 + c * 64;
        __syncthreads();
#pragma unroll
        for (int it = 0; it < 2; ++it) {
            int idx = tid + it * 256;
            int r = idx >> 3, u = (idx & 7) * 8;
            int j = kc + r;
            uint4 kv = make_uint4(0, 0, 0, 0), vv = make_uint4(0, 0, 0, 0);
            if (j >= 0) {
                kv = *(const uint4*)(qkv + (rowbase + j) * 2304 + 768 + h * HEAD + u);
                vv = *(const uint4*)(qkv + (rowbase + j) * 2304 + 1536 + h * HEAD + u);
            }
            *(uint4*)(&Ks[r][u]) = kv;
            const u16* pv = (const u16*)&vv;
#pragma unroll
            for (int i = 0; i < 8; i++) Vt[u + i][r] = pv[i];
        }
        __syncthreads();

        bf16x8 aq0 = *(const bf16x8*)(&Qs[wave * 16 + lm][g * 8]);
        bf16x8 aq1 = *(const bf16x8*)(&Qs[wave * 16 + lm][32 + g * 8]);
        f32x4 s[4];
#pragma unroll
        for (int kf = 0; kf < 4; kf++) {
            bf16x8 b0 = *(const bf16x8*)(&Ks[kf * 16 + lm][g * 8]);
            bf16x8 b1 = *(const bf16x8*)(&Ks[kf * 16 + lm][32 + g * 8]);
            f32x4 z = (f32x4)0.0f;
            z = __builtin_amdgcn_mfma_f32_16x16x32_bf16(aq0, b0, z, 0, 0, 0);
            z = __builtin_amdgcn_mfma_f32_16x16x32_bf16(aq1, b1, z, 0, 0, 0);
            s[kf] = z;
        }

        float sv[4][4], mc[4];
#pragma unroll
        for (int r = 0; r < 4; r++) mc[r] = -INFINITY;
#pragma unroll
        for (int kf = 0; kf < 4; kf++) {
            int j = kc + kf * 16 + lm;
#pragma unroll
            for (int r = 0; r < 4; r++) {
                int i = q0 + wave * 16 + g * 4 + r;
                bool valid = (j >= 0) && (j <= i) && (j >= i - 511);
                float v = valid ? s[kf][r] * 0.125f : -INFINITY;
                sv[kf][r] = v;
                mc[r] = fmaxf(mc[r], v);
            }
        }
#pragma unroll
        for (int off = 1; off < 16; off <<= 1)
#pragma unroll
            for (int r = 0; r < 4; r++) mc[r] = fmaxf(mc[r], __shfl_xor(mc[r], off, 64));

        float alpha[4], mn[4];
#pragma unroll
        for (int r = 0; r < 4; r++) {
            mn[r] = fmaxf(m_r[r], mc[r]);
            alpha[r] = (mn[r] > -1e37f) ? __expf(m_r[r] - mn[r]) : 1.0f;
            m_r[r] = mn[r];
        }
        float ps[4][4], rs[4] = {0.f, 0.f, 0.f, 0.f};
#pragma unroll
        for (int kf = 0; kf < 4; kf++)
#pragma unroll
            for (int r = 0; r < 4; r++) {
                float p = (sv[kf][r] > -1e37f) ? __expf(sv[kf][r] - mn[r]) : 0.0f;
                ps[kf][r] = p;
                rs[r] += p;
            }
#pragma unroll
        for (int off = 1; off < 16; off <<= 1)
#pragma unroll
            for (int r = 0; r < 4; r++) rs[r] += __shfl_xor(rs[r], off, 64);
#pragma unroll
        for (int r = 0; r < 4; r++) l_r[r] = l_r[r] * alpha[r] + rs[r];

#pragma unroll
        for (int kf = 0; kf < 4; kf++)
#pragma unroll
            for (int r = 0; r < 4; r++) Ps[wave][g * 4 + r][kf * 16 + lm] = f2bf(ps[kf][r]);

#pragma unroll
        for (int d = 0; d < 4; d++)
#pragma unroll
            for (int r = 0; r < 4; r++) o[d][r] *= alpha[r];

        bf16x8 pa0 = *(const bf16x8*)(&Ps[wave][lm][g * 8]);
        bf16x8 pa1 = *(const bf16x8*)(&Ps[wave][lm][32 + g * 8]);
#pragma unroll
        for (int d = 0; d < 4; d++) {
            bf16x8 b0 = *(const bf16x8*)(&Vt[d * 16 + lm][g * 8]);
            bf16x8 b1 = *(const bf16x8*)(&Vt[d * 16 + lm][32 + g * 8]);
            o[d] = __builtin_amdgcn_mfma_f32_16x16x32_bf16(pa0, b0, o[d], 0, 0, 0);
            o[d] = __builtin_amdgcn_mfma_f32_16x16x32_bf16(pa1, b1, o[d], 0, 0, 0);
        }
    }

#pragma unroll
    for (int d = 0; d < 4; d++) {
        int dd = d * 16 + lm;
#pragma unroll
        for (int r = 0; r < 4; r++) {
            int i = q0 + wave * 16 + g * 4 + r;
            float v = o[d][r] / l_r[r];
            Out[(rowbase + i) * 3840 + h * HEAD + dd] = f2bf(v);
        }
    }
}

extern "C" void kernel_launch(void* const* d_in, const int* in_sizes, int n_in,
                              void* d_out, int out_size, void* d_ws, size_t ws_size,
                              hipStream_t stream) {
    const int* tokens   = (const int*)d_in[0];
    const void* ages    = d_in[1];
    const void* embed   = d_in[2];
    const void* in_norm_w  = d_in[3];
    const void* out_norm_w = d_in[4];
    const void* norm_w     = d_in[5];
    const void* attn_W     = d_in[6];
    const void* attn_b     = d_in[7];
    const void* in_W       = d_in[8];
    const void* in_b       = d_in[9];
    const void* out_W      = d_in[10];
    const void* out_b      = d_in[11];

    char* w = (char*)d_ws;
    int* flags  = (int*)w;   w += 256;
    float* x    = (float*)w; w += (size_t)BS * H_SIZE * 4;
    u16* xn     = (u16*)w;   w += (size_t)BS * H_SIZE * 2;
    u16* qkv    = (u16*)w;   w += (size_t)BS * 2304 * 2;
    u16* comb   = (u16*)w;   w += (size_t)BS * 3840 * 2;
    float* sinb = (float*)w; w += (size_t)BS * 32 * 4;
    float* cosb = (float*)w; w += (size_t)BS * 32 * 4;
    u16* wtf    = (u16*)w;   w += (size_t)N_LAYERS * 5376 * 768 * 2;
    u16* wto    = (u16*)w;   w += (size_t)N_LAYERS * 768 * 3840 * 2;
    u16* biasb  = (u16*)w;   w += (size_t)(6*2304 + 6*3072 + 6*768) * 2;

    u16* ab_b = biasb;
    u16* ib_b = biasb + 6 * 2304;
    u16* ob_b = ib_b + 6 * 3072;

    const size_t LFS = (size_t)5376 * 768;

    probe_kernel<<<1, 64, 0, stream>>>((const u16*)embed, tokens, flags);
    sincos_kernel<<<(BS * 32 + 255) / 256, 256, 0, stream>>>(ages, sinb, cosb, flags);
    embed_norm_kernel<<<BS / 4, 256, 0, stream>>>(tokens, embed, in_norm_w, x, flags);
    bias_conv_kernel<<<(6 * (2304 + 3072 + 768) + 255) / 256, 256, 0, stream>>>(
        attn_b, in_b, out_b, biasb, flags);

    wtrans_kernel<<<dim3(2304 / 64, 768 / 64, N_LAYERS), 256, 0, stream>>>(
        attn_W, wtf, 768, 2304, LFS, flags);
    wtrans_kernel<<<dim3(3072 / 64, 768 / 64, N_LAYERS), 256, 0, stream>>>(
        in_W, wtf + (size_t)2304 * 768, 768, 3072, LFS, flags);
    wtrans_kernel<<<dim3(768 / 64, 3840 / 64, N_LAYERS), 256, 0, stream>>>(
        out_W, wto, 3840, 768, (size_t)768 * 3840, flags);

    for (int l = 0; l < N_LAYERS; ++l) {
        rmsnorm_kernel<<<BS / 4, 256, 0, stream>>>(x, norm_w, (size_t)l * H_SIZE, xn, 0, flags);
        gemm_kernel<0, 256, 256, 4><<<dim3(5376 / 256, BS / 256), 512, 0, stream>>>(
            xn, wtf + (size_t)l * LFS, ab_b + l * 2304, ib_b + l * 3072,
            nullptr, qkv, comb, H_SIZE, sinb, cosb);
        attn_kernel<<<dim3(SEQ / 64, N_HEADS, BATCH), 256, 0, stream>>>(qkv, comb);
        gemm_kernel<2, 128, 64, 4><<<dim3(768 / 64, BS / 128), 256, 0, stream>>>(
            comb, wto + (size_t)l * 768 * 3840, ob_b + l * 768, nullptr,
            x, nullptr, nullptr, H_SIZE + INTER, nullptr, nullptr);
    }
    rmsnorm_kernel<<<BS / 4, 256, 0, stream>>>(x, out_norm_w, 0, d_out, 1, flags);
}

// Round 10
// 1757.634 us; speedup vs baseline: 1.1189x; 1.1189x over previous
//
#include <hip/hip_runtime.h>
#include <hip/hip_bf16.h>
#include <math.h>

#define H_SIZE 768
#define N_HEADS 12
#define HEAD 64
#define INTER 3072
#define N_LAYERS 6
#define BATCH 4
#define SEQ 2048
#define BS (BATCH*SEQ)
#define EPSV 1e-6f

typedef __attribute__((ext_vector_type(8))) short bf16x8;
typedef __attribute__((ext_vector_type(4))) float f32x4;
typedef unsigned short u16;

__device__ inline float bf2f(u16 v) {
    union { float f; unsigned u; } x; x.u = ((unsigned)v) << 16; return x.f;
}
__device__ inline u16 f2bf(float f) {
    union { float f; unsigned u; } x; x.f = f;
    unsigned u = x.u;
    return (u16)((u + 0x7FFFu + ((u >> 16) & 1u)) >> 16);
}

// async global->LDS, 16B per lane. LDS dest = wave-uniform base + lane*16.
__device__ __forceinline__ void stage16(const u16* g, u16* ldsbase) {
    __builtin_amdgcn_global_load_lds((const __attribute__((address_space(1))) void*)g,
                                     (__attribute__((address_space(3))) void*)ldsbase,
                                     16, 0, 0);
}

// ---------------- dtype probe ----------------
__global__ void probe_kernel(const u16* __restrict__ embed, const int* __restrict__ tokens,
                             int* __restrict__ flags) {
    if (threadIdx.x == 0 && blockIdx.x == 0) {
        int good = 0, evenzero = 0;
        for (int i = 0; i < 128; i++) {
            u16 h = embed[i];
            int e = (h >> 7) & 0xFF;
            if (h == 0 || (e >= 87 && e <= 133)) good++;
            if ((i & 1) == 0 && h == 0) evenzero++;
        }
        flags[0] = (evenzero >= 48) ? 1 : ((good >= 110) ? 0 : 1);
        int z = 0;
        for (int i = 0; i < 64; i++) if (tokens[2 * i + 1] == 0) z++;
        flags[1] = (z >= 60) ? 1 : 0;
    }
}

// ---------------- sincos table ----------------
__global__ __launch_bounds__(256) void sincos_kernel(const void* __restrict__ ages,
                                                     float* __restrict__ SIN,
                                                     float* __restrict__ COS,
                                                     const int* __restrict__ flags) {
    int idx = blockIdx.x * 256 + threadIdx.x;
    if (idx >= BS * 32) return;
    bool f32in = flags[0] != 0;
    int row = idx >> 5, f = idx & 31;
    float age = f32in ? ((const float*)ages)[row] : bf2f(((const u16*)ages)[row]);
    float inv = expf(-(2.0f * (float)f / 31.0f) * 9.210340371976184f);
    float t = age * inv;
    SIN[idx] = sinf(t);
    COS[idx] = cosf(t);
}

// ---------------- weight transpose+convert (batched over layers via z) ----------------
__global__ __launch_bounds__(256) void wtrans_kernel(const void* __restrict__ Wsrc,
                                                     u16* __restrict__ Wt,
                                                     int K, int N, size_t ltstride,
                                                     const int* __restrict__ flags) {
    __shared__ u16 tile[64][72];
    bool f32in = flags[0] != 0;
    int l = blockIdx.z;
    const float* W32 = (const float*)Wsrc + (size_t)l * K * N;
    const u16*   W16 = (const u16*)Wsrc + (size_t)l * K * N;
    u16* out = Wt + (size_t)l * ltstride;
    int k0 = blockIdx.y * 64, n0 = blockIdx.x * 64;
    int t = threadIdx.x;
    int kk = t >> 3, nn = (t & 7) * 8;
#pragma unroll
    for (int it = 0; it < 2; it++) {
        int kr = kk + it * 32;
        u16 tmp[8];
        if (f32in) {
            const float* src = W32 + (size_t)(k0 + kr) * N + n0 + nn;
            float4 f0 = *(const float4*)src, f1 = *(const float4*)(src + 4);
            tmp[0] = f2bf(f0.x); tmp[1] = f2bf(f0.y); tmp[2] = f2bf(f0.z); tmp[3] = f2bf(f0.w);
            tmp[4] = f2bf(f1.x); tmp[5] = f2bf(f1.y); tmp[6] = f2bf(f1.z); tmp[7] = f2bf(f1.w);
        } else {
            uint4 v = *(const uint4*)(W16 + (size_t)(k0 + kr) * N + n0 + nn);
            const u16* pv = (const u16*)&v;
#pragma unroll
            for (int i = 0; i < 8; i++) tmp[i] = pv[i];
        }
        *(uint4*)(&tile[kr][nn]) = *(const uint4*)tmp;
    }
    __syncthreads();
    int n = t >> 3, kq = (t & 7) * 8;
#pragma unroll
    for (int it = 0; it < 2; it++) {
        int nr = n + it * 32;
        u16 tmp[8];
#pragma unroll
        for (int i = 0; i < 8; i++) tmp[i] = tile[kq + i][nr];
        *(uint4*)(out + (size_t)(n0 + nr) * K + k0 + kq) = *(const uint4*)tmp;
    }
}

// ---------------- bias convert to bf16 ----------------
__global__ __launch_bounds__(256) void bias_conv_kernel(const void* __restrict__ ab,
                                                        const void* __restrict__ ib,
                                                        const void* __restrict__ ob,
                                                        u16* __restrict__ dst,
                                                        const int* __restrict__ flags) {
    int i = blockIdx.x * 256 + threadIdx.x;
    bool f32in = flags[0] != 0;
    const int A = 6 * 2304, B = 6 * 3072, C = 6 * 768;
    if (i < A) dst[i] = f32in ? f2bf(((const float*)ab)[i]) : ((const u16*)ab)[i];
    else if (i < A + B) { int j = i - A; dst[i] = f32in ? f2bf(((const float*)ib)[j]) : ((const u16*)ib)[j]; }
    else if (i < A + B + C) { int j = i - A - B; dst[i] = f32in ? f2bf(((const float*)ob)[j]) : ((const u16*)ob)[j]; }
}

// ---------------- embed gather + rmsnorm (f32 out) ----------------
__global__ __launch_bounds__(256) void embed_norm_kernel(const int* __restrict__ tokens,
                                                         const void* __restrict__ embed,
                                                         const void* __restrict__ wbase,
                                                         float* __restrict__ X,
                                                         const int* __restrict__ flags) {
    int row = blockIdx.x * 4 + (threadIdx.x >> 6);
    int lane = threadIdx.x & 63;
    bool f32in = flags[0] != 0;
    bool i64 = flags[1] != 0;
    int tok = i64 ? tokens[2 * row] : tokens[row];
    tok &= 65535;
    const u16* er16 = (const u16*)embed + (size_t)tok * H_SIZE;
    const float* er32 = (const float*)embed + (size_t)tok * H_SIZE;
    const u16* w16 = (const u16*)wbase;
    const float* w32 = (const float*)wbase;
    float v[12]; float ss = 0.f;
#pragma unroll
    for (int k = 0; k < 12; k++) {
        int i = lane + k * 64;
        float t = f32in ? er32[i] : bf2f(er16[i]);
        v[k] = t; ss += t * t;
    }
#pragma unroll
    for (int off = 1; off < 64; off <<= 1) ss += __shfl_xor(ss, off, 64);
    float scale = rsqrtf(ss * (1.0f / 768.0f) + EPSV);
#pragma unroll
    for (int k = 0; k < 12; k++) {
        int i = lane + k * 64;
        float wv = f32in ? w32[i] : bf2f(w16[i]);
        X[(size_t)row * H_SIZE + i] = v[k] * scale * wv;
    }
}

// ---------------- rmsnorm f32 -> bf16 / flag-typed final ----------------
__global__ __launch_bounds__(256) void rmsnorm_kernel(const float* __restrict__ X,
                                                      const void* __restrict__ wbase, size_t woff,
                                                      void* __restrict__ Y, int outMode,
                                                      const int* __restrict__ flags) {
    int row = blockIdx.x * 4 + (threadIdx.x >> 6);
    int lane = threadIdx.x & 63;
    bool f32in = flags[0] != 0;
    const u16* w16 = (const u16*)wbase + woff;
    const float* w32 = (const float*)wbase + woff;
    const float* xr = X + (size_t)row * H_SIZE;
    float v[12]; float ss = 0.f;
#pragma unroll
    for (int k = 0; k < 12; k++) { v[k] = xr[lane + k * 64]; ss += v[k] * v[k]; }
#pragma unroll
    for (int off = 1; off < 64; off <<= 1) ss += __shfl_xor(ss, off, 64);
    float scale = rsqrtf(ss * (1.0f / 768.0f) + EPSV);
    bool of32 = outMode && f32in;
#pragma unroll
    for (int k = 0; k < 12; k++) {
        int i = lane + k * 64;
        float wv = f32in ? w32[i] : bf2f(w16[i]);
        float val = v[k] * scale * wv;
        if (of32) ((float*)Y)[(size_t)row * H_SIZE + i] = val;
        else      ((u16*)Y)[(size_t)row * H_SIZE + i] = f2bf(val);
    }
}

// ---------------- bf16 MFMA GEMM: 3-buffer depth-2 pipeline, counted vmcnt (r8 config) ----------------
template <int EPI, int BN, int MGRP>
__global__ __launch_bounds__(256) void gemm_kernel(const u16* __restrict__ A,
                                                   const u16* __restrict__ Wt,
                                                   const u16* __restrict__ abias,
                                                   const u16* __restrict__ bbias,
                                                   float* __restrict__ Cf,
                                                   u16* __restrict__ qkvb,
                                                   u16* __restrict__ combb,
                                                   int K,
                                                   const float* __restrict__ SIN,
                                                   const float* __restrict__ COS) {
    constexpr int NF = BN / 32;
    __shared__ u16 Al[3][128][32];
    __shared__ u16 Bl[3][BN][32];
    const int tid = threadIdx.x;
    const int lane = tid & 63, wave = tid >> 6;
    const int wm = wave >> 1, wn = wave & 1;
    const int lm = lane & 15, g = lane >> 4;

    const int nx = gridDim.x;
    const int mpx = gridDim.y >> 3;
    int linear = blockIdx.y * nx + blockIdx.x;
    const int xcd = linear & 7;
    int wch = linear >> 3;
    const int grpsz = MGRP * nx;
    int grp = wch / grpsz;
    int rem = wch - grp * grpsz;
    int n_idx = rem / MGRP;
    int m_loc = grp * MGRP + (rem - n_idx * MGRP);
    const int m0 = (xcd * mpx + m_loc) * 128;
    const int n0 = n_idx * BN;

    f32x4 acc[4][NF];
#pragma unroll
    for (int i = 0; i < 4; i++)
#pragma unroll
        for (int j = 0; j < NF; j++) acc[i][j] = (f32x4)0.0f;

    const int swcol = ((lane & 3) ^ ((lane >> 3) & 3)) * 8;
    const u16* ga = A  + (size_t)(m0 + wave * 16 + (lane >> 2)) * K + swcol;
    const u16* gb = Wt + (size_t)(n0 + wave * 16 + (lane >> 2)) * K + swcol;
    const size_t row64 = (size_t)64 * K;

    auto STAGE = [&](int bi, int kk) {
        stage16(ga + kk, &Al[bi][wave * 16][0]);
        stage16(ga + row64 + kk, &Al[bi][64 + wave * 16][0]);
        stage16(gb + kk, &Bl[bi][wave * 16][0]);
        if constexpr (BN == 128) stage16(gb + row64 + kk, &Bl[bi][64 + wave * 16][0]);
    };

    STAGE(0, 0);
    STAGE(1, 32);
    int cur = 0;
    const int cc = (g ^ ((lm >> 1) & 3)) * 8;
    for (int k0 = 0; k0 < K; k0 += 32) {
        if (k0 + 32 < K) {
            if constexpr (BN == 128) asm volatile("s_waitcnt vmcnt(4)" ::: "memory");
            else                     asm volatile("s_waitcnt vmcnt(3)" ::: "memory");
        } else {
            asm volatile("s_waitcnt vmcnt(0)" ::: "memory");
        }
        __builtin_amdgcn_s_barrier();
        if (k0 + 64 < K) {
            int nx2 = cur + 2; if (nx2 >= 3) nx2 -= 3;
            STAGE(nx2, k0 + 64);
        }
        bf16x8 a[4], b[NF];
#pragma unroll
        for (int i = 0; i < 4; i++) a[i] = *(const bf16x8*)(&Al[cur][wm * 64 + i * 16 + lm][cc]);
#pragma unroll
        for (int j = 0; j < NF; j++) b[j] = *(const bf16x8*)(&Bl[cur][wn * (BN / 2) + j * 16 + lm][cc]);
#pragma unroll
        for (int i = 0; i < 4; i++)
#pragma unroll
            for (int j = 0; j < NF; j++)
                acc[i][j] = __builtin_amdgcn_mfma_f32_16x16x32_bf16(a[i], b[j], acc[i][j], 0, 0, 0);
        cur += 1; if (cur >= 3) cur = 0;
    }

#pragma unroll
    for (int i = 0; i < 4; i++) {
        int mbase = m0 + wm * 64 + i * 16 + g * 4;
#pragma unroll
        for (int j = 0; j < NF; j++) {
            int n = n0 + wn * (BN / 2) + j * 16 + lm;
            float bv;
            if (EPI == 0) bv = (n < 2304) ? bf2f(abias[n]) : bf2f(bbias[n - 2304]);
            else          bv = bf2f(abias[n]);
#pragma unroll
            for (int r = 0; r < 4; r++) {
                float v = acc[i][j][r] + bv;
                int mm = mbase + r;
                if (EPI == 0) {
                    float p = __shfl_xor(v, 1);
                    if (n < 2304) {
                        float outv = v;
                        if (n < 1536) {
                            int f = (n >> 1) & 31;
                            float c = COS[mm * 32 + f], s = SIN[mm * 32 + f];
                            outv = (n & 1) ? (v * c + p * s) : (v * c - p * s);
                        }
                        qkvb[(size_t)mm * 2304 + n] = f2bf(outv);
                    } else {
                        float u = 0.7978845608f * (v + 0.044715f * v * v * v);
                        float e = __expf(2.0f * u);
                        float th = 1.0f - 2.0f / (e + 1.0f);
                        combb[(size_t)mm * 3840 + (n - 1536)] = f2bf(0.5f * v * (1.0f + th));
                    }
                } else {
                    Cf[(size_t)mm * 768 + n] += v;
                }
            }
        }
    }
}

// ---------------- windowed flash attention: 128-query blocks, 8 waves, 10 chunks ----------------
__global__ __launch_bounds__(512) void attn_kernel(const u16* __restrict__ qkv,
                                                   u16* __restrict__ Out) {
    __shared__ u16 Qs[128][72];
    __shared__ u16 Ks[64][72];
    __shared__ u16 Vt[64][72];
    __shared__ u16 Ps[8][16][72];

    const int tid = threadIdx.x;
    const int lane = tid & 63, wave = tid >> 6;
    const int lm = lane & 15, g = lane >> 4;
    const int q0 = blockIdx.x * 128;
    const int h = blockIdx.y;
    const int b = blockIdx.z;
    const size_t rowbase = (size_t)b * SEQ;

#pragma unroll
    for (int it = 0; it < 2; ++it) {
        int idx = tid + it * 512;
        int r = idx >> 3, u = (idx & 7) * 8;
        uint4 v = *(const uint4*)(qkv + (rowbase + q0 + r) * 2304 + h * HEAD + u);
        *(uint4*)(&Qs[r][u]) = v;
    }

    float m_r[4], l_r[4];
    f32x4 o[4];
#pragma unroll
    for (int r = 0; r < 4; r++) { m_r[r] = -INFINITY; l_r[r] = 0.f; }
#pragma unroll
    for (int d = 0; d < 4; d++) o[d] = (f32x4)0.0f;

    // chunks c = 0..9 cover keys [q0-512, q0+128); skip fully-invalid (kc+63 < 0)
    const int c_start = (q0 < 512) ? ((512 - q0) >> 6) : 0;
    for (int c = c_start; c < 10; ++c) {
        int kc = q0 - 512 + c * 64;
        __syncthreads();
        {
            int r = tid >> 3, u = (tid & 7) * 8;
            int j = kc + r;
            uint4 kv = make_uint4(0, 0, 0, 0), vv = make_uint4(0, 0, 0, 0);
            if (j >= 0) {
                kv = *(const uint4*)(qkv + (rowbase + j) * 2304 + 768 + h * HEAD + u);
                vv = *(const uint4*)(qkv + (rowbase + j) * 2304 + 1536 + h * HEAD + u);
            }
            *(uint4*)(&Ks[r][u]) = kv;
            const u16* pv = (const u16*)&vv;
#pragma unroll
            for (int i = 0; i < 8; i++) Vt[u + i][r] = pv[i];
        }
        __syncthreads();

        bf16x8 aq0 = *(const bf16x8*)(&Qs[wave * 16 + lm][g * 8]);
        bf16x8 aq1 = *(const bf16x8*)(&Qs[wave * 16 + lm][32 + g * 8]);
        f32x4 s[4];
#pragma unroll
        for (int kf = 0; kf < 4; kf++) {
            bf16x8 b0 = *(const bf16x8*)(&Ks[kf * 16 + lm][g * 8]);
            bf16x8 b1 = *(const bf16x8*)(&Ks[kf * 16 + lm][32 + g * 8]);
            f32x4 z = (f32x4)0.0f;
            z = __builtin_amdgcn_mfma_f32_16x16x32_bf16(aq0, b0, z, 0, 0, 0);
            z = __builtin_amdgcn_mfma_f32_16x16x32_bf16(aq1, b1, z, 0, 0, 0);
            s[kf] = z;
        }

        float sv[4][4], mc[4];
#pragma unroll
        for (int r = 0; r < 4; r++) mc[r] = -INFINITY;
#pragma unroll
        for (int kf = 0; kf < 4; kf++) {
            int j = kc + kf * 16 + lm;
#pragma unroll
            for (int r = 0; r < 4; r++) {
                int i = q0 + wave * 16 + g * 4 + r;
                bool valid = (j >= 0) && (j <= i) && (j >= i - 511);
                float v = valid ? s[kf][r] * 0.125f : -INFINITY;
                sv[kf][r] = v;
                mc[r] = fmaxf(mc[r], v);
            }
        }
#pragma unroll
        for (int off = 1; off < 16; off <<= 1)
#pragma unroll
            for (int r = 0; r < 4; r++) mc[r] = fmaxf(mc[r], __shfl_xor(mc[r], off, 64));

        float alpha[4], mn[4];
#pragma unroll
        for (int r = 0; r < 4; r++) {
            mn[r] = fmaxf(m_r[r], mc[r]);
            alpha[r] = (mn[r] > -1e37f) ? __expf(m_r[r] - mn[r]) : 1.0f;
            m_r[r] = mn[r];
        }
        float ps[4][4], rs[4] = {0.f, 0.f, 0.f, 0.f};
#pragma unroll
        for (int kf = 0; kf < 4; kf++)
#pragma unroll
            for (int r = 0; r < 4; r++) {
                float p = (sv[kf][r] > -1e37f) ? __expf(sv[kf][r] - mn[r]) : 0.0f;
                ps[kf][r] = p;
                rs[r] += p;
            }
#pragma unroll
        for (int off = 1; off < 16; off <<= 1)
#pragma unroll
            for (int r = 0; r < 4; r++) rs[r] += __shfl_xor(rs[r], off, 64);
#pragma unroll
        for (int r = 0; r < 4; r++) l_r[r] = l_r[r] * alpha[r] + rs[r];

#pragma unroll
        for (int kf = 0; kf < 4; kf++)
#pragma unroll
            for (int r = 0; r < 4; r++) Ps[wave][g * 4 + r][kf * 16 + lm] = f2bf(ps[kf][r]);

#pragma unroll
        for (int d = 0; d < 4; d++)
#pragma unroll
            for (int r = 0; r < 4; r++) o[d][r] *= alpha[r];

        bf16x8 pa0 = *(const bf16x8*)(&Ps[wave][lm][g * 8]);
        bf16x8 pa1 = *(const bf16x8*)(&Ps[wave][lm][32 + g * 8]);
#pragma unroll
        for (int d = 0; d < 4; d++) {
            bf16x8 b0 = *(const bf16x8*)(&Vt[d * 16 + lm][g * 8]);
            bf16x8 b1 = *(const bf16x8*)(&Vt[d * 16 + lm][32 + g * 8]);
            o[d] = __builtin_amdgcn_mfma_f32_16x16x32_bf16(pa0, b0, o[d], 0, 0, 0);
            o[d] = __builtin_amdgcn_mfma_f32_16x16x32_bf16(pa1, b1, o[d], 0, 0, 0);
        }
    }

#pragma unroll
    for (int d = 0; d < 4; d++) {
        int dd = d * 16 + lm;
#pragma unroll
        for (int r = 0; r < 4; r++) {
            int i = q0 + wave * 16 + g * 4 + r;
            float v = o[d][r] / l_r[r];
            Out[(rowbase + i) * 3840 + h * HEAD + dd] = f2bf(v);
        }
    }
}

extern "C" void kernel_launch(void* const* d_in, const int* in_sizes, int n_in,
                              void* d_out, int out_size, void* d_ws, size_t ws_size,
                              hipStream_t stream) {
    const int* tokens   = (const int*)d_in[0];
    const void* ages    = d_in[1];
    const void* embed   = d_in[2];
    const void* in_norm_w  = d_in[3];
    const void* out_norm_w = d_in[4];
    const void* norm_w     = d_in[5];
    const void* attn_W     = d_in[6];
    const void* attn_b     = d_in[7];
    const void* in_W       = d_in[8];
    const void* in_b       = d_in[9];
    const void* out_W      = d_in[10];
    const void* out_b      = d_in[11];

    char* w = (char*)d_ws;
    int* flags  = (int*)w;   w += 256;
    float* x    = (float*)w; w += (size_t)BS * H_SIZE * 4;
    u16* xn     = (u16*)w;   w += (size_t)BS * H_SIZE * 2;
    u16* qkv    = (u16*)w;   w += (size_t)BS * 2304 * 2;
    u16* comb   = (u16*)w;   w += (size_t)BS * 3840 * 2;
    float* sinb = (float*)w; w += (size_t)BS * 32 * 4;
    float* cosb = (float*)w; w += (size_t)BS * 32 * 4;
    u16* wtf    = (u16*)w;   w += (size_t)N_LAYERS * 5376 * 768 * 2;
    u16* wto    = (u16*)w;   w += (size_t)N_LAYERS * 768 * 3840 * 2;
    u16* biasb  = (u16*)w;   w += (size_t)(6*2304 + 6*3072 + 6*768) * 2;

    u16* ab_b = biasb;
    u16* ib_b = biasb + 6 * 2304;
    u16* ob_b = ib_b + 6 * 3072;

    const size_t LFS = (size_t)5376 * 768;

    probe_kernel<<<1, 64, 0, stream>>>((const u16*)embed, tokens, flags);
    sincos_kernel<<<(BS * 32 + 255) / 256, 256, 0, stream>>>(ages, sinb, cosb, flags);
    embed_norm_kernel<<<BS / 4, 256, 0, stream>>>(tokens, embed, in_norm_w, x, flags);
    bias_conv_kernel<<<(6 * (2304 + 3072 + 768) + 255) / 256, 256, 0, stream>>>(
        attn_b, in_b, out_b, biasb, flags);

    wtrans_kernel<<<dim3(2304 / 64, 768 / 64, N_LAYERS), 256, 0, stream>>>(
        attn_W, wtf, 768, 2304, LFS, flags);
    wtrans_kernel<<<dim3(3072 / 64, 768 / 64, N_LAYERS), 256, 0, stream>>>(
        in_W, wtf + (size_t)2304 * 768, 768, 3072, LFS, flags);
    wtrans_kernel<<<dim3(768 / 64, 3840 / 64, N_LAYERS), 256, 0, stream>>>(
        out_W, wto, 3840, 768, (size_t)768 * 3840, flags);

    for (int l = 0; l < N_LAYERS; ++l) {
        rmsnorm_kernel<<<BS / 4, 256, 0, stream>>>(x, norm_w, (size_t)l * H_SIZE, xn, 0, flags);
        gemm_kernel<0, 128, 8><<<dim3(5376 / 128, BS / 128), 256, 0, stream>>>(
            xn, wtf + (size_t)l * LFS, ab_b + l * 2304, ib_b + l * 3072,
            nullptr, qkv, comb, H_SIZE, sinb, cosb);
        attn_kernel<<<dim3(SEQ / 128, N_HEADS, BATCH), 512, 0, stream>>>(qkv, comb);
        gemm_kernel<2, 64, 4><<<dim3(768 / 64, BS / 128), 256, 0, stream>>>(
            comb, wto + (size_t)l * 768 * 3840, ob_b + l * 768, nullptr,
            x, nullptr, nullptr, H_SIZE + INTER, nullptr, nullptr);
    }
    rmsnorm_kernel<<<BS / 4, 256, 0, stream>>>(x, out_norm_w, 0, d_out, 1, flags);
}